// Round 11
// baseline (288.068 us; speedup 1.0000x reference)
//
#include <hip/hip_runtime.h>
#include <hip/hip_bf16.h>

#define D 64
#define NB_HIST 256          // partition blocks (fixed ranges, pass A == pass B)
#define MAXBK 512            // supports N <= 131072 (buckets of 256 nodes)

typedef float vfloat4 __attribute__((ext_vector_type(4)));

__device__ __forceinline__ unsigned short f2bf(float f) {
    union { float f; unsigned u; } v; v.f = f;
    unsigned r = (v.u + 0x7FFF + ((v.u >> 16) & 1)) >> 16;   // RNE
    return (unsigned short)r;
}
__device__ __forceinline__ float bflo(unsigned u) {
    union { unsigned u; float f; } v; v.u = u << 16; return v.f;
}
__device__ __forceinline__ float bfhi(unsigned u) {
    union { unsigned u; float f; } v; v.u = u & 0xFFFF0000u; return v.f;
}

// hn layout: SLICED — hs[slice][node][16] bf16, slice = cols [16s, 16s+16)
// slice table = N*32 B = 3.2 MB -> fits one XCD L2.

// =============== pass A: fused {per-block LDS bucket histogram} + GEMM1 ===============
__global__ __launch_bounds__(256) void passA_gemm(
    const int* __restrict__ dst, int* __restrict__ blockCounts, int E, int per, int NBK,
    const float* __restrict__ X, const float* __restrict__ W,
    unsigned short* __restrict__ hn, int N)
{
    int tid = threadIdx.x;

    if ((int)blockIdx.x < NB_HIST) {
        __shared__ int hist[MAXBK];
        for (int i = tid; i < NBK; i += 256) hist[i] = 0;
        __syncthreads();
        int lo = blockIdx.x * per, hi = min(E, lo + per);   // per % 4 == 0
        for (int i = lo + tid * 4; i < hi; i += 1024) {
            if (i + 3 < hi) {
                int4 d4 = *(const int4*)(dst + i);
                atomicAdd(&hist[d4.x >> 8], 1);
                atomicAdd(&hist[d4.y >> 8], 1);
                atomicAdd(&hist[d4.z >> 8], 1);
                atomicAdd(&hist[d4.w >> 8], 1);
            } else {
                for (int k = i; k < hi; ++k) atomicAdd(&hist[dst[k] >> 8], 1);
            }
        }
        __syncthreads();
        for (int i = tid; i < NBK; i += 256)
            blockCounts[(size_t)blockIdx.x * NBK + i] = hist[i];
        return;
    }

    __shared__ float sW[D * D];
    __shared__ float sX[32 * D];
    int rowBase = ((int)blockIdx.x - NB_HIST) * 32;

    for (int i = tid; i < 1024; i += 256)
        ((vfloat4*)sW)[i] = ((const vfloat4*)W)[i];
    for (int i = tid; i < 512; i += 256) {
        int r = rowBase + (i >> 4);
        vfloat4 v = (vfloat4)0.0f;
        if (r < N) v = __builtin_nontemporal_load(((const vfloat4*)X) + rowBase * 16 + i);
        ((vfloat4*)sX)[i] = v;
    }
    __syncthreads();

    int wave = tid >> 6, lane = tid & 63;
    float accv[8];
#pragma unroll
    for (int r = 0; r < 8; ++r) accv[r] = 0.0f;
    int xoff = (wave * 8) * D;
#pragma unroll 8
    for (int k = 0; k < D; ++k) {
        float wv = sW[k * D + lane];
#pragma unroll
        for (int r = 0; r < 8; ++r)
            accv[r] += sX[xoff + r * D + k] * wv;
    }
    size_t sbase = (size_t)(lane >> 4) * ((size_t)N * 16);  // slice base (ushort units)
    int within = lane & 15;
#pragma unroll
    for (int r = 0; r < 8; ++r) {
        int row = rowBase + wave * 8 + r;
        if (row < N) hn[sbase + (size_t)row * 16 + within] = f2bf(accv[r]);
    }
}

// =============== C1: per-bucket exclusive scan over the 256 blocks ===============
__global__ __launch_bounds__(256) void scan_cols(
    const int* __restrict__ blockCounts, int* __restrict__ partial,
    int* __restrict__ totals, int NBK)
{
    int wave = threadIdx.x >> 6, lane = threadIdx.x & 63;
    int k = blockIdx.x * 4 + wave;
    if (k >= NBK) return;
    int carry = 0;
    for (int base = 0; base < NB_HIST; base += 64) {
        int b = base + lane;
        int v = blockCounts[(size_t)b * NBK + k];
        int inc = v;
        for (int d = 1; d < 64; d <<= 1) {
            int t = __shfl_up(inc, d, 64);
            if (lane >= d) inc += t;
        }
        partial[(size_t)k * NB_HIST + b] = inc - v + carry;
        carry += __shfl(inc, 63, 64);
    }
    if (lane == 0) totals[k] = carry;
}

// =============== C2: exclusive scan of bucket totals (single wave) ===============
__global__ void scan_buckets(const int* __restrict__ totals, int* __restrict__ bofs, int NBK) {
    int lane = threadIdx.x;
    int carry = 0;
    for (int base = 0; base < NBK; base += 64) {
        int i = base + lane;
        int v = (i < NBK) ? totals[i] : 0;
        int inc = v;
        for (int d = 1; d < 64; d <<= 1) {
            int t = __shfl_up(inc, d, 64);
            if (lane >= d) inc += t;
        }
        if (i < NBK) bofs[i] = inc - v + carry;
        carry += __shfl(inc, 63, 64);
    }
}

// =============== pass B: scatter edges into bucket-grouped order (LDS cursors) ===============
__global__ __launch_bounds__(256) void passB(
    const int* __restrict__ src, const int* __restrict__ dst,
    const int* __restrict__ bofs, const int* __restrict__ partial,
    int* __restrict__ bucketed, int E, int per, int NBK)
{
    __shared__ int cur[MAXBK];
    int tid = threadIdx.x, b = blockIdx.x;
    for (int i = tid; i < NBK; i += 256)
        cur[i] = bofs[i] + partial[(size_t)i * NB_HIST + b];
    __syncthreads();
    int lo = b * per, hi = min(E, lo + per);
    for (int i = lo + tid * 4; i < hi; i += 1024) {
        if (i + 3 < hi) {
            int4 d4 = *(const int4*)(dst + i);
            int4 s4 = *(const int4*)(src + i);
            int p0 = atomicAdd(&cur[d4.x >> 8], 1);
            int p1 = atomicAdd(&cur[d4.y >> 8], 1);
            int p2 = atomicAdd(&cur[d4.z >> 8], 1);
            int p3 = atomicAdd(&cur[d4.w >> 8], 1);
            bucketed[p0] = (s4.x << 8) | (d4.x & 255);
            bucketed[p1] = (s4.y << 8) | (d4.y & 255);
            bucketed[p2] = (s4.z << 8) | (d4.z & 255);
            bucketed[p3] = (s4.w << 8) | (d4.w & 255);
        } else {
            for (int k = i; k < hi; ++k) {
                int d = dst[k], s = src[k];
                int pos = atomicAdd(&cur[d >> 8], 1);
                bucketed[pos] = (s << 8) | (d & 255);
            }
        }
    }
}

// =============== level 2: per-bucket CSR build + deg/dinv/ofs + hn scale (sliced) ===============
__global__ __launch_bounds__(256) void build_csr_scale(
    const int* __restrict__ bucketed, const int* __restrict__ bofs,
    const int* __restrict__ totals, int* __restrict__ deg, float* __restrict__ dinv,
    int* __restrict__ ofs, int* __restrict__ csr,
    unsigned short* __restrict__ hn, int N)
{
    __shared__ int h[256];
    __shared__ int scn[256];
    __shared__ float sdv[256];
    int tid = threadIdx.x, k = blockIdx.x;
    int e0 = bofs[k], e1 = e0 + totals[k];
    int node = k * 256 + tid;

    h[tid] = 0;
    __syncthreads();
    for (int i = e0 + tid; i < e1; i += 256)
        atomicAdd(&h[bucketed[i] & 255], 1);
    __syncthreads();

    int mydeg = h[tid];
    scn[tid] = mydeg;
    __syncthreads();
    for (int d2 = 1; d2 < 256; d2 <<= 1) {
        int t = (tid >= d2) ? scn[tid - d2] : 0;
        __syncthreads();
        scn[tid] += t;
        __syncthreads();
    }
    int myofs = scn[tid] - mydeg;

    float dv = rsqrtf((float)(mydeg + 1));
    sdv[tid] = dv;
    if (node < N) {
        deg[node]  = mydeg;
        dinv[node] = dv;
        ofs[node]  = e0 + myofs;
    }

    h[tid] = myofs;                 // reuse as write cursor
    __syncthreads();
    for (int i = e0 + tid; i < e1; i += 256) {
        int v = bucketed[i];
        int pos = atomicAdd(&h[v & 255], 1);
        csr[e0 + pos] = v >> 8;
    }

    // scale this bucket's hn rows by dinv (in-place, bf16, sliced layout)
    __syncthreads();
    int4* hp = (int4*)hn;
    size_t sstride = (size_t)N * 2;               // int4 per slice
    for (int c = tid; c < 2048; c += 256) {       // 4 slices x 256 rows x 2 int4
        int slice = c >> 9;
        int r = (c >> 1) & 255;
        int half = c & 1;
        int n2 = k * 256 + r;
        if (n2 < N) {
            float f = sdv[r];
            size_t idx = (size_t)slice * sstride + (size_t)n2 * 2 + half;
            int4 hv = hp[idx];
            unsigned r0 = (unsigned)f2bf(bflo(hv.x) * f) | ((unsigned)f2bf(bfhi(hv.x) * f) << 16);
            unsigned r1 = (unsigned)f2bf(bflo(hv.y) * f) | ((unsigned)f2bf(bfhi(hv.y) * f) << 16);
            unsigned r2 = (unsigned)f2bf(bflo(hv.z) * f) | ((unsigned)f2bf(bfhi(hv.z) * f) << 16);
            unsigned r3 = (unsigned)f2bf(bflo(hv.w) * f) | ((unsigned)f2bf(bfhi(hv.w) * f) << 16);
            hp[idx] = make_int4((int)r0, (int)r1, (int)r2, (int)r3);
        }
    }
}

// =============== GEMM2: hn = bf16((h1 @ W) * dinv[row]), sliced output ===============
__global__ __launch_bounds__(256) void gemm2(
    const float* __restrict__ X, const float* __restrict__ W,
    const float* __restrict__ dinv, unsigned short* __restrict__ hn, int N)
{
    __shared__ float sW[D * D];
    __shared__ float sX[32 * D];
    int tid = threadIdx.x;
    int rowBase = blockIdx.x * 32;

    for (int i = tid; i < 1024; i += 256)
        ((vfloat4*)sW)[i] = ((const vfloat4*)W)[i];
    for (int i = tid; i < 512; i += 256) {
        int r = rowBase + (i >> 4);
        vfloat4 v = (vfloat4)0.0f;
        if (r < N) v = ((const vfloat4*)X)[rowBase * 16 + i];
        ((vfloat4*)sX)[i] = v;
    }
    __syncthreads();

    int wave = tid >> 6, lane = tid & 63;
    float accv[8];
#pragma unroll
    for (int r = 0; r < 8; ++r) accv[r] = 0.0f;
    int xoff = (wave * 8) * D;
#pragma unroll 8
    for (int k = 0; k < D; ++k) {
        float wv = sW[k * D + lane];
#pragma unroll
        for (int r = 0; r < 8; ++r)
            accv[r] += sX[xoff + r * D + k] * wv;
    }
    size_t sbase = (size_t)(lane >> 4) * ((size_t)N * 16);
    int within = lane & 15;
#pragma unroll
    for (int r = 0; r < 8; ++r) {
        int row = rowBase + wave * 8 + r;
        if (row < N) hn[sbase + (size_t)row * 16 + within] = f2bf(accv[r] * dinv[row]);
    }
}

// =============== aggregate: XCD-sliced pull, 2-lane group per node ===============
// slice = blockIdx & 3 (round-robin -> slice s pinned to XCDs {s, s+4});
// 128 nodes/block; pair of lanes gathers the node's 32 B row-slice (2 x int4);
// out line (16 fp32 = 64 B) written fully by the pair. hn pre-scaled by dinv[src].
__global__ __launch_bounds__(256) void aggregate_relu(
    const int* __restrict__ ofs, const int* __restrict__ deg,
    const int* __restrict__ csr, const unsigned short* __restrict__ hn,
    const float* __restrict__ dinv, const float* __restrict__ bias,
    float* __restrict__ out, int N)
{
    int slice = blockIdx.x & 3;
    int tblk  = blockIdx.x >> 2;
    int tid   = threadIdx.x;
    int pair  = tid >> 1, half = tid & 1;
    int node  = tblk * 128 + pair;
    bool live = (node < N);

    const int4* base = (const int4*)hn + (size_t)slice * ((size_t)N * 2);
    float2 a0 = {0.f, 0.f}, a1 = {0.f, 0.f}, a2 = {0.f, 0.f}, a3 = {0.f, 0.f};

    int s0 = 0, cnt = 0;
    if (live) {
        s0  = ofs[node];
        cnt = deg[node];
        int4 h = base[(size_t)node * 2 + half];      // self loop (pre-scaled)
        a0.x += bflo(h.x); a0.y += bfhi(h.x);
        a1.x += bflo(h.y); a1.y += bfhi(h.y);
        a2.x += bflo(h.z); a2.y += bfhi(h.z);
        a3.x += bflo(h.w); a3.y += bfhi(h.w);
    }

    const int* cp = csr + s0;
    int j = 0;
    for (; j + 1 < cnt; j += 2) {                    // 2 gathers in flight per pair
        int sA = cp[j], sB = cp[j + 1];
        int4 hA = base[(size_t)sA * 2 + half];
        int4 hB = base[(size_t)sB * 2 + half];
        a0.x += bflo(hA.x); a0.y += bfhi(hA.x);
        a1.x += bflo(hA.y); a1.y += bfhi(hA.y);
        a2.x += bflo(hA.z); a2.y += bfhi(hA.z);
        a3.x += bflo(hA.w); a3.y += bfhi(hA.w);
        a0.x += bflo(hB.x); a0.y += bfhi(hB.x);
        a1.x += bflo(hB.y); a1.y += bfhi(hB.y);
        a2.x += bflo(hB.z); a2.y += bfhi(hB.z);
        a3.x += bflo(hB.w); a3.y += bfhi(hB.w);
    }
    if (j < cnt) {
        int sA = cp[j];
        int4 hA = base[(size_t)sA * 2 + half];
        a0.x += bflo(hA.x); a0.y += bfhi(hA.x);
        a1.x += bflo(hA.y); a1.y += bfhi(hA.y);
        a2.x += bflo(hA.z); a2.y += bfhi(hA.z);
        a3.x += bflo(hA.w); a3.y += bfhi(hA.w);
    }

    if (live) {
        float dw = dinv[node];
        float4 b0 = ((const float4*)bias)[slice * 4 + half * 2];
        float4 b1 = ((const float4*)bias)[slice * 4 + half * 2 + 1];
        float4 o0, o1;
        o0.x = fmaxf(a0.x * dw + b0.x, 0.f);
        o0.y = fmaxf(a0.y * dw + b0.y, 0.f);
        o0.z = fmaxf(a1.x * dw + b0.z, 0.f);
        o0.w = fmaxf(a1.y * dw + b0.w, 0.f);
        o1.x = fmaxf(a2.x * dw + b1.x, 0.f);
        o1.y = fmaxf(a2.y * dw + b1.y, 0.f);
        o1.z = fmaxf(a3.x * dw + b1.z, 0.f);
        o1.w = fmaxf(a3.y * dw + b1.w, 0.f);
        ((float4*)out)[(size_t)node * 16 + slice * 4 + half * 2]     = o0;
        ((float4*)out)[(size_t)node * 16 + slice * 4 + half * 2 + 1] = o1;
    }
}

// =============== launcher ===============

extern "C" void kernel_launch(void* const* d_in, const int* in_sizes, int n_in,
                              void* d_out, int out_size, void* d_ws, size_t ws_size,
                              hipStream_t stream) {
    const float* x   = (const float*)d_in[0];
    const int*   ei  = (const int*)d_in[1];   // [2, E] int32
    const float* W1  = (const float*)d_in[2];
    const float* b1  = (const float*)d_in[3];
    const float* W2  = (const float*)d_in[4];
    const float* b2  = (const float*)d_in[5];

    int N = in_sizes[0] / D;
    int E = in_sizes[1] / 2;
    const int* src = ei;
    const int* dst = ei + E;
    int NBK = (N + 255) >> 8;
    int per = (((E + NB_HIST - 1) / NB_HIST) + 3) & ~3;

    // workspace layout (bytes, ~30 MB)
    char* ws = (char*)d_ws;
    int*            blockCounts = (int*)(ws + 0x00000000);  // NB_HIST*NBK
    int*            partial     = (int*)(ws + 0x00080000);  // NBK*NB_HIST
    int*            totals      = (int*)(ws + 0x00100000);  // NBK
    int*            bofs        = (int*)(ws + 0x00110000);  // NBK
    int*            deg         = (int*)(ws + 0x00120000);  // N
    float*          dinv        = (float*)(ws + 0x00190000);// N
    int*            ofs         = (int*)(ws + 0x00200000);  // N
    int*            bucketed    = (int*)(ws + 0x00280000);  // E
    int*            csr         = (int*)(ws + 0x00A00000);  // E
    unsigned short* hn          = (unsigned short*)(ws + 0x01100000); // N*D bf16, sliced
    float*          outF        = (float*)d_out;

    int nb_G = (N + 31) / 32;
    int nb_A = ((N + 127) / 128) * 4;         // node-blocks x 4 slices

    passA_gemm<<<NB_HIST + nb_G, 256, 0, stream>>>(dst, blockCounts, E, per, NBK, x, W1, hn, N);
    scan_cols<<<(NBK + 3) / 4, 256, 0, stream>>>(blockCounts, partial, totals, NBK);
    scan_buckets<<<1, 64, 0, stream>>>(totals, bofs, NBK);
    passB<<<NB_HIST, 256, 0, stream>>>(src, dst, bofs, partial, bucketed, E, per, NBK);
    build_csr_scale<<<NBK, 256, 0, stream>>>(bucketed, bofs, totals, deg, dinv, ofs, csr, hn, N);

    aggregate_relu<<<nb_A, 256, 0, stream>>>(ofs, deg, csr, hn, dinv, b1, outF, N);
    gemm2<<<nb_G, 256, 0, stream>>>(outF, W2, dinv, hn, N);
    aggregate_relu<<<nb_A, 256, 0, stream>>>(ofs, deg, csr, hn, dinv, b2, outF, N);
}

// Round 12
// 240.140 us; speedup vs baseline: 1.1996x; 1.1996x over previous
//
#include <hip/hip_runtime.h>
#include <hip/hip_bf16.h>

#define D 64
#define NB_HIST 256          // partition blocks (fixed ranges, pass A == pass B)
#define MAXBK 512            // supports N <= 131072 (buckets of 256 nodes)

typedef float vfloat4 __attribute__((ext_vector_type(4)));

__device__ __forceinline__ unsigned short f2bf(float f) {
    union { float f; unsigned u; } v; v.f = f;
    unsigned r = (v.u + 0x7FFF + ((v.u >> 16) & 1)) >> 16;   // RNE
    return (unsigned short)r;
}
__device__ __forceinline__ float bflo(unsigned u) {
    union { unsigned u; float f; } v; v.u = u << 16; return v.f;
}
__device__ __forceinline__ float bfhi(unsigned u) {
    union { unsigned u; float f; } v; v.u = u & 0xFFFF0000u; return v.f;
}

// =============== pass A: fused {per-block LDS bucket histogram} + GEMM1 ===============
__global__ __launch_bounds__(256) void passA_gemm(
    const int* __restrict__ dst, int* __restrict__ blockCounts, int E, int per, int NBK,
    const float* __restrict__ X, const float* __restrict__ W,
    unsigned short* __restrict__ hn, int N)
{
    int tid = threadIdx.x;

    if ((int)blockIdx.x < NB_HIST) {
        __shared__ int hist[MAXBK];
        for (int i = tid; i < NBK; i += 256) hist[i] = 0;
        __syncthreads();
        int lo = blockIdx.x * per, hi = min(E, lo + per);   // per % 4 == 0
        for (int i = lo + tid * 4; i < hi; i += 1024) {
            if (i + 3 < hi) {
                int4 d4 = *(const int4*)(dst + i);
                atomicAdd(&hist[d4.x >> 8], 1);
                atomicAdd(&hist[d4.y >> 8], 1);
                atomicAdd(&hist[d4.z >> 8], 1);
                atomicAdd(&hist[d4.w >> 8], 1);
            } else {
                for (int k = i; k < hi; ++k) atomicAdd(&hist[dst[k] >> 8], 1);
            }
        }
        __syncthreads();
        for (int i = tid; i < NBK; i += 256)
            blockCounts[(size_t)blockIdx.x * NBK + i] = hist[i];
        return;
    }

    __shared__ float sW[D * D];
    __shared__ float sX[32 * D];
    int rowBase = ((int)blockIdx.x - NB_HIST) * 32;

    for (int i = tid; i < 1024; i += 256)
        ((vfloat4*)sW)[i] = ((const vfloat4*)W)[i];
    for (int i = tid; i < 512; i += 256) {
        int r = rowBase + (i >> 4);
        vfloat4 v = (vfloat4)0.0f;
        if (r < N) v = __builtin_nontemporal_load(((const vfloat4*)X) + rowBase * 16 + i);
        ((vfloat4*)sX)[i] = v;
    }
    __syncthreads();

    int wave = tid >> 6, lane = tid & 63;
    float accv[8];
#pragma unroll
    for (int r = 0; r < 8; ++r) accv[r] = 0.0f;
    int xoff = (wave * 8) * D;
#pragma unroll 8
    for (int k = 0; k < D; ++k) {
        float wv = sW[k * D + lane];
#pragma unroll
        for (int r = 0; r < 8; ++r)
            accv[r] += sX[xoff + r * D + k] * wv;
    }
#pragma unroll
    for (int r = 0; r < 8; ++r) {
        int row = rowBase + wave * 8 + r;
        if (row < N) hn[(size_t)row * D + lane] = f2bf(accv[r]);
    }
}

// =============== C1: per-bucket exclusive scan over the 256 blocks ===============
__global__ __launch_bounds__(256) void scan_cols(
    const int* __restrict__ blockCounts, int* __restrict__ partial,
    int* __restrict__ totals, int NBK)
{
    int wave = threadIdx.x >> 6, lane = threadIdx.x & 63;
    int k = blockIdx.x * 4 + wave;
    if (k >= NBK) return;
    int carry = 0;
    for (int base = 0; base < NB_HIST; base += 64) {
        int b = base + lane;
        int v = blockCounts[(size_t)b * NBK + k];
        int inc = v;
        for (int d = 1; d < 64; d <<= 1) {
            int t = __shfl_up(inc, d, 64);
            if (lane >= d) inc += t;
        }
        partial[(size_t)k * NB_HIST + b] = inc - v + carry;
        carry += __shfl(inc, 63, 64);
    }
    if (lane == 0) totals[k] = carry;
}

// =============== C2: exclusive scan of bucket totals (single wave) ===============
__global__ void scan_buckets(const int* __restrict__ totals, int* __restrict__ bofs, int NBK) {
    int lane = threadIdx.x;
    int carry = 0;
    for (int base = 0; base < NBK; base += 64) {
        int i = base + lane;
        int v = (i < NBK) ? totals[i] : 0;
        int inc = v;
        for (int d = 1; d < 64; d <<= 1) {
            int t = __shfl_up(inc, d, 64);
            if (lane >= d) inc += t;
        }
        if (i < NBK) bofs[i] = inc - v + carry;
        carry += __shfl(inc, 63, 64);
    }
}

// =============== pass B: scatter edges into bucket-grouped order (LDS cursors) ===============
__global__ __launch_bounds__(256) void passB(
    const int* __restrict__ src, const int* __restrict__ dst,
    const int* __restrict__ bofs, const int* __restrict__ partial,
    int* __restrict__ bucketed, int E, int per, int NBK)
{
    __shared__ int cur[MAXBK];
    int tid = threadIdx.x, b = blockIdx.x;
    for (int i = tid; i < NBK; i += 256)
        cur[i] = bofs[i] + partial[(size_t)i * NB_HIST + b];
    __syncthreads();
    int lo = b * per, hi = min(E, lo + per);
    for (int i = lo + tid * 4; i < hi; i += 1024) {
        if (i + 3 < hi) {
            int4 d4 = *(const int4*)(dst + i);
            int4 s4 = *(const int4*)(src + i);
            int p0 = atomicAdd(&cur[d4.x >> 8], 1);
            int p1 = atomicAdd(&cur[d4.y >> 8], 1);
            int p2 = atomicAdd(&cur[d4.z >> 8], 1);
            int p3 = atomicAdd(&cur[d4.w >> 8], 1);
            bucketed[p0] = (s4.x << 8) | (d4.x & 255);
            bucketed[p1] = (s4.y << 8) | (d4.y & 255);
            bucketed[p2] = (s4.z << 8) | (d4.z & 255);
            bucketed[p3] = (s4.w << 8) | (d4.w & 255);
        } else {
            for (int k = i; k < hi; ++k) {
                int d = dst[k], s = src[k];
                int pos = atomicAdd(&cur[d >> 8], 1);
                bucketed[pos] = (s << 8) | (d & 255);
            }
        }
    }
}

// =============== level 2: per-bucket CSR build + deg/dinv/ofs + hn scale ===============
__global__ __launch_bounds__(256) void build_csr_scale(
    const int* __restrict__ bucketed, const int* __restrict__ bofs,
    const int* __restrict__ totals, int* __restrict__ deg, float* __restrict__ dinv,
    int* __restrict__ ofs, int* __restrict__ csr,
    unsigned short* __restrict__ hn, int N)
{
    __shared__ int h[256];
    __shared__ int scn[256];
    __shared__ float sdv[256];
    int tid = threadIdx.x, k = blockIdx.x;
    int e0 = bofs[k], e1 = e0 + totals[k];
    int node = k * 256 + tid;

    h[tid] = 0;
    __syncthreads();
    for (int i = e0 + tid; i < e1; i += 256)
        atomicAdd(&h[bucketed[i] & 255], 1);
    __syncthreads();

    int mydeg = h[tid];
    scn[tid] = mydeg;
    __syncthreads();
    for (int d2 = 1; d2 < 256; d2 <<= 1) {
        int t = (tid >= d2) ? scn[tid - d2] : 0;
        __syncthreads();
        scn[tid] += t;
        __syncthreads();
    }
    int myofs = scn[tid] - mydeg;

    float dv = rsqrtf((float)(mydeg + 1));
    sdv[tid] = dv;
    if (node < N) {
        deg[node]  = mydeg;
        dinv[node] = dv;
        ofs[node]  = e0 + myofs;
    }

    h[tid] = myofs;                 // reuse as write cursor
    __syncthreads();
    for (int i = e0 + tid; i < e1; i += 256) {
        int v = bucketed[i];
        int pos = atomicAdd(&h[v & 255], 1);
        csr[e0 + pos] = v >> 8;
    }

    __syncthreads();
    int4* hp = (int4*)hn;
    for (int c = tid; c < 2048; c += 256) {       // 256 rows x 8 int4 chunks
        int r = c >> 3;
        int n2 = k * 256 + r;
        if (n2 < N) {
            float f = sdv[r];
            size_t idx = (size_t)n2 * 8 + (c & 7);
            int4 hv = hp[idx];
            unsigned r0 = (unsigned)f2bf(bflo(hv.x) * f) | ((unsigned)f2bf(bfhi(hv.x) * f) << 16);
            unsigned r1 = (unsigned)f2bf(bflo(hv.y) * f) | ((unsigned)f2bf(bfhi(hv.y) * f) << 16);
            unsigned r2 = (unsigned)f2bf(bflo(hv.z) * f) | ((unsigned)f2bf(bfhi(hv.z) * f) << 16);
            unsigned r3 = (unsigned)f2bf(bflo(hv.w) * f) | ((unsigned)f2bf(bfhi(hv.w) * f) << 16);
            hp[idx] = make_int4((int)r0, (int)r1, (int)r2, (int)r3);
        }
    }
}

// =============== GEMM2: hn = bf16((relu_h1_bf16 @ W) * dinv[row]) ===============
// h1 input is bf16 (written by agg1); staged to fp32 in LDS.
__global__ __launch_bounds__(256) void gemm2(
    const unsigned short* __restrict__ h1b, const float* __restrict__ W,
    const float* __restrict__ dinv, unsigned short* __restrict__ hn, int N)
{
    __shared__ float sW[D * D];
    __shared__ float sX[32 * D];
    int tid = threadIdx.x;
    int rowBase = blockIdx.x * 32;

    for (int i = tid; i < 1024; i += 256)
        ((vfloat4*)sW)[i] = ((const vfloat4*)W)[i];
    {
        // 32 rows x 8 chunks of 8 bf16; one int4 (8 bf16) per thread
        int r = tid >> 3, c8 = tid & 7;
        int row = rowBase + r;
        int4 hv = make_int4(0, 0, 0, 0);
        if (row < N) hv = ((const int4*)h1b)[(size_t)row * 8 + c8];
        float* dst8 = &sX[r * D + c8 * 8];
        dst8[0] = bflo(hv.x); dst8[1] = bfhi(hv.x);
        dst8[2] = bflo(hv.y); dst8[3] = bfhi(hv.y);
        dst8[4] = bflo(hv.z); dst8[5] = bfhi(hv.z);
        dst8[6] = bflo(hv.w); dst8[7] = bfhi(hv.w);
    }
    __syncthreads();

    int wave = tid >> 6, lane = tid & 63;
    float accv[8];
#pragma unroll
    for (int r = 0; r < 8; ++r) accv[r] = 0.0f;
    int xoff = (wave * 8) * D;
#pragma unroll 8
    for (int k = 0; k < D; ++k) {
        float wv = sW[k * D + lane];
#pragma unroll
        for (int r = 0; r < 8; ++r)
            accv[r] += sX[xoff + r * D + k] * wv;
    }
#pragma unroll
    for (int r = 0; r < 8; ++r) {
        int row = rowBase + wave * 8 + r;
        if (row < N) hn[(size_t)row * D + lane] = f2bf(accv[r] * dinv[row]);
    }
}

// =============== aggregate: one 8-lane group per node, 8 nodes per wave ===============
// lane sub owns cols sub*8..sub*8+7 (one int4 of the bf16 row); accs final per
// group (no cross-group reduction / no shfl). hn pre-scaled by dinv[src].
// BF16OUT: layer-1 -> bf16 h1 (one int4/lane); else fp32 final (two float4/lane).
template <bool BF16OUT>
__global__ __launch_bounds__(256) void aggregate_relu(
    const int* __restrict__ ofs, const int* __restrict__ deg,
    const int* __restrict__ csr, const unsigned short* __restrict__ hn,
    const float* __restrict__ dinv, const float* __restrict__ bias,
    void* __restrict__ outv, int N)
{
    int t    = blockIdx.x * 256 + threadIdx.x;
    int lane = threadIdx.x & 63;
    int grp  = lane >> 3, sub = lane & 7;
    int node = (t >> 6) * 8 + grp;
    bool live = (node < N);

    const int4* hrow = (const int4*)hn;
    float2 a0 = {0.f, 0.f}, a1 = {0.f, 0.f}, a2 = {0.f, 0.f}, a3 = {0.f, 0.f};

    int s0 = 0, cnt = 0;
    if (live) {
        s0  = ofs[node];
        cnt = deg[node];
        int4 h = hrow[(size_t)node * 8 + sub];       // self loop (pre-scaled)
        a0.x += bflo(h.x); a0.y += bfhi(h.x);
        a1.x += bflo(h.y); a1.y += bfhi(h.y);
        a2.x += bflo(h.z); a2.y += bfhi(h.z);
        a3.x += bflo(h.w); a3.y += bfhi(h.w);
    }

    const int* cp = csr + s0;
    int j = 0;
    for (; j + 3 < cnt; j += 4) {                    // 4 gathers in flight per lane
        int sA = cp[j], sB = cp[j + 1], sC = cp[j + 2], sD = cp[j + 3];
        int4 hA = hrow[(size_t)sA * 8 + sub];
        int4 hB = hrow[(size_t)sB * 8 + sub];
        int4 hC = hrow[(size_t)sC * 8 + sub];
        int4 hD = hrow[(size_t)sD * 8 + sub];
        a0.x += bflo(hA.x); a0.y += bfhi(hA.x);
        a1.x += bflo(hA.y); a1.y += bfhi(hA.y);
        a2.x += bflo(hA.z); a2.y += bfhi(hA.z);
        a3.x += bflo(hA.w); a3.y += bfhi(hA.w);
        a0.x += bflo(hB.x); a0.y += bfhi(hB.x);
        a1.x += bflo(hB.y); a1.y += bfhi(hB.y);
        a2.x += bflo(hB.z); a2.y += bfhi(hB.z);
        a3.x += bflo(hB.w); a3.y += bfhi(hB.w);
        a0.x += bflo(hC.x); a0.y += bfhi(hC.x);
        a1.x += bflo(hC.y); a1.y += bfhi(hC.y);
        a2.x += bflo(hC.z); a2.y += bfhi(hC.z);
        a3.x += bflo(hC.w); a3.y += bfhi(hC.w);
        a0.x += bflo(hD.x); a0.y += bfhi(hD.x);
        a1.x += bflo(hD.y); a1.y += bfhi(hD.y);
        a2.x += bflo(hD.z); a2.y += bfhi(hD.z);
        a3.x += bflo(hD.w); a3.y += bfhi(hD.w);
    }
    for (; j < cnt; ++j) {
        int sA = cp[j];
        int4 hA = hrow[(size_t)sA * 8 + sub];
        a0.x += bflo(hA.x); a0.y += bfhi(hA.x);
        a1.x += bflo(hA.y); a1.y += bfhi(hA.y);
        a2.x += bflo(hA.z); a2.y += bfhi(hA.z);
        a3.x += bflo(hA.w); a3.y += bfhi(hA.w);
    }

    if (live) {
        float dw = dinv[node];
        float4 b0 = ((const float4*)bias)[sub * 2];
        float4 b1 = ((const float4*)bias)[sub * 2 + 1];
        float o0 = fmaxf(a0.x * dw + b0.x, 0.f);
        float o1 = fmaxf(a0.y * dw + b0.y, 0.f);
        float o2 = fmaxf(a1.x * dw + b0.z, 0.f);
        float o3 = fmaxf(a1.y * dw + b0.w, 0.f);
        float o4 = fmaxf(a2.x * dw + b1.x, 0.f);
        float o5 = fmaxf(a2.y * dw + b1.y, 0.f);
        float o6 = fmaxf(a3.x * dw + b1.z, 0.f);
        float o7 = fmaxf(a3.y * dw + b1.w, 0.f);
        if (BF16OUT) {
            unsigned r0 = (unsigned)f2bf(o0) | ((unsigned)f2bf(o1) << 16);
            unsigned r1 = (unsigned)f2bf(o2) | ((unsigned)f2bf(o3) << 16);
            unsigned r2 = (unsigned)f2bf(o4) | ((unsigned)f2bf(o5) << 16);
            unsigned r3 = (unsigned)f2bf(o6) | ((unsigned)f2bf(o7) << 16);
            ((int4*)outv)[(size_t)node * 8 + sub] =
                make_int4((int)r0, (int)r1, (int)r2, (int)r3);
        } else {
            float4 v0 = make_float4(o0, o1, o2, o3);
            float4 v1 = make_float4(o4, o5, o6, o7);
            ((float4*)outv)[(size_t)node * 16 + sub * 2]     = v0;
            ((float4*)outv)[(size_t)node * 16 + sub * 2 + 1] = v1;
        }
    }
}

// =============== launcher ===============

extern "C" void kernel_launch(void* const* d_in, const int* in_sizes, int n_in,
                              void* d_out, int out_size, void* d_ws, size_t ws_size,
                              hipStream_t stream) {
    const float* x   = (const float*)d_in[0];
    const int*   ei  = (const int*)d_in[1];   // [2, E] int32
    const float* W1  = (const float*)d_in[2];
    const float* b1  = (const float*)d_in[3];
    const float* W2  = (const float*)d_in[4];
    const float* b2  = (const float*)d_in[5];

    int N = in_sizes[0] / D;
    int E = in_sizes[1] / 2;
    const int* src = ei;
    const int* dst = ei + E;
    int NBK = (N + 255) >> 8;
    int per = (((E + NB_HIST - 1) / NB_HIST) + 3) & ~3;

    // workspace layout (bytes, ~44 MB)
    char* ws = (char*)d_ws;
    int*            blockCounts = (int*)(ws + 0x00000000);  // NB_HIST*NBK
    int*            partial     = (int*)(ws + 0x00080000);  // NBK*NB_HIST
    int*            totals      = (int*)(ws + 0x00100000);  // NBK
    int*            bofs        = (int*)(ws + 0x00110000);  // NBK
    int*            deg         = (int*)(ws + 0x00120000);  // N
    float*          dinv        = (float*)(ws + 0x00190000);// N
    int*            ofs         = (int*)(ws + 0x00200000);  // N
    int*            bucketed    = (int*)(ws + 0x00280000);  // E
    int*            csr         = (int*)(ws + 0x00A00000);  // E
    unsigned short* hn          = (unsigned short*)(ws + 0x01100000); // N*D bf16 (12.8 MB)
    unsigned short* h1b         = (unsigned short*)(ws + 0x01D80000); // N*D bf16 (12.8 MB)
    float*          outF        = (float*)d_out;

    int nb_G = (N + 31) / 32;
    int nb_A = (N + 31) / 32;                 // agg: 8 nodes/wave, 32/block

    passA_gemm<<<NB_HIST + nb_G, 256, 0, stream>>>(dst, blockCounts, E, per, NBK, x, W1, hn, N);
    scan_cols<<<(NBK + 3) / 4, 256, 0, stream>>>(blockCounts, partial, totals, NBK);
    scan_buckets<<<1, 64, 0, stream>>>(totals, bofs, NBK);
    passB<<<NB_HIST, 256, 0, stream>>>(src, dst, bofs, partial, bucketed, E, per, NBK);
    build_csr_scale<<<NBK, 256, 0, stream>>>(bucketed, bofs, totals, deg, dinv, ofs, csr, hn, N);

    // layer 1 aggregate -> h1 (bf16, in ws)
    aggregate_relu<true><<<nb_A, 256, 0, stream>>>(ofs, deg, csr, hn, dinv, b1, (void*)h1b, N);
    // layer 2 GEMM: hn = bf16((h1 @ W2) * dinv)
    gemm2<<<nb_G, 256, 0, stream>>>(h1b, W2, dinv, hn, N);
    // layer 2 aggregate -> final out (fp32, d_out)
    aggregate_relu<false><<<nb_A, 256, 0, stream>>>(ofs, deg, csr, hn, dinv, b2, (void*)outF, N);
}